// Round 2
// baseline (356.444 us; speedup 1.0000x reference)
//
#include <hip/hip_runtime.h>

#define VOCAB 128000
#define EMBED 256
#define BATCH 64
#define TBLOCK 2048
#define ROWS (BATCH * TBLOCK)   // 131072 rows

#define RPW 8                   // rows per wave (8 outstanding gathers)
#define WPB 4                   // waves per 256-thread block
#define ROWS_PER_BLOCK (RPW * WPB)  // 32

typedef float v4f __attribute__((ext_vector_type(4)));  // clang-native float4

// One wave (64 lanes) processes RPW rows: 64 lanes x float4 = 256 floats = one row.
// All 8 row indices are fetched up front (two broadcast int4 loads), then all 8
// random 1KB row-gathers are issued back-to-back for maximum MLP. Outputs are
// streamed with nontemporal stores so the 128MB embedding table stays resident
// in L2/L3 across iterations.
__global__ __launch_bounds__(256) void embed_expnorm_kernel(
    const int* __restrict__ idx,
    const float* __restrict__ emb,
    float* __restrict__ logits,
    float* __restrict__ probs)
{
    const int lane = threadIdx.x & 63;
    const int wid  = blockIdx.x * WPB + (threadIdx.x >> 6);
    const long long rowbase = (long long)wid * RPW;

    // --- load 8 row indices (wave-uniform addresses -> broadcast loads) ---
    const int4* ip = reinterpret_cast<const int4*>(idx + rowbase);
    const int4 i0 = ip[0];
    const int4 i1 = ip[1];
    int rows[RPW];
    rows[0] = i0.x; rows[1] = i0.y; rows[2] = i0.z; rows[3] = i0.w;
    rows[4] = i1.x; rows[5] = i1.y; rows[6] = i1.z; rows[7] = i1.w;

    // --- issue all 8 gathers (independent -> 8 loads in flight) ---
    v4f v[RPW];
    #pragma unroll
    for (int r = 0; r < RPW; ++r) {
        const v4f* rowp =
            reinterpret_cast<const v4f*>(emb + (long long)rows[r] * EMBED);
        v[r] = rowp[lane];
    }

    // --- per-lane partial sums of exp ---
    float s[RPW];
    #pragma unroll
    for (int r = 0; r < RPW; ++r) {
        const float ex = __expf(v[r].x);
        const float ey = __expf(v[r].y);
        const float ez = __expf(v[r].z);
        const float ew = __expf(v[r].w);
        s[r] = (ex + ey) + (ez + ew);
    }

    // --- 8 parallel 64-lane butterfly reductions (shuffles pipeline across r) ---
    #pragma unroll
    for (int m = 1; m < 64; m <<= 1) {
        #pragma unroll
        for (int r = 0; r < RPW; ++r)
            s[r] += __shfl_xor(s[r], m, 64);
    }

    // --- normalize (recompute exp: transcendental pipe is ~free) + stream out ---
    v4f* lp = reinterpret_cast<v4f*>(logits);
    v4f* pp = reinterpret_cast<v4f*>(probs);
    #pragma unroll
    for (int r = 0; r < RPW; ++r) {
        const float inv = 1.0f / s[r];
        v4f p;
        p.x = __expf(v[r].x) * inv;
        p.y = __expf(v[r].y) * inv;
        p.z = __expf(v[r].z) * inv;
        p.w = __expf(v[r].w) * inv;

        const long long off = (rowbase + r) * (EMBED / 4) + lane;
        __builtin_nontemporal_store(v[r], lp + off);
        __builtin_nontemporal_store(p,    pp + off);
    }
}

extern "C" void kernel_launch(void* const* d_in, const int* in_sizes, int n_in,
                              void* d_out, int out_size, void* d_ws, size_t ws_size,
                              hipStream_t stream) {
    const int*   idx = (const int*)d_in[0];
    const float* emb = (const float*)d_in[1];

    float* out    = (float*)d_out;
    float* logits = out;                              // [ROWS, EMBED]
    float* probs  = out + (long long)ROWS * EMBED;    // [ROWS, EMBED]

    const int blocks = ROWS / ROWS_PER_BLOCK;         // 4096
    embed_expnorm_kernel<<<blocks, 256, 0, stream>>>(idx, emb, logits, probs);
}